// Round 5
// baseline (337.458 us; speedup 1.0000x reference)
//
#include <hip/hip_runtime.h>

// Problem constants (B=8, T=4096, D=64, M=1024, N=32768)
#define T_DIM 4096
#define D_DIM 64
#define M_DIM 1024
#define N_ROWS 32768
#define TR 32   // rows (tokens) per workgroup
#define NT 512  // threads per block (8 waves)
#define SC_STRIDE (M_DIM + 4)

typedef __attribute__((ext_vector_type(8))) short bf16x8;
typedef __attribute__((ext_vector_type(4))) float f32x4;

// ws layout: floats [0,1024)=||e||^2, [1024,2048)=counts, [2048]=loss accum.
// shorts from float index 4096 (byte 16384): EH[65536], EL[65536], ETH[65536], ETL[65536]
#define WS_BF16_OFF 4096

__device__ __forceinline__ short f2bfs(float f) {
  union { float f; unsigned u; } v; v.f = f;
  unsigned r = v.u + 0x7fffu + ((v.u >> 16) & 1u);  // RNE
  return (short)(r >> 16);
}
__device__ __forceinline__ float bf2f(short h) {
  union { unsigned u; float f; } v; v.u = ((unsigned)(unsigned short)h) << 16;
  return v.f;
}
// 8 consecutive fp32 -> hi/lo bf16x8
__device__ __forceinline__ void cvt8(const float* p, bf16x8& h8, bf16x8& l8) {
  float4 a = *(const float4*)p, b = *(const float4*)(p + 4);
  float v[8] = {a.x, a.y, a.z, a.w, b.x, b.y, b.z, b.w};
#pragma unroll
  for (int i = 0; i < 8; ++i) {
    short h = f2bfs(v[i]);
    h8[i] = h;
    l8[i] = f2bfs(v[i] - bf2f(h));
  }
}

// split embedding into hi/lo bf16 (row-major + transposed, all coalesced via
// LDS tile), and fold in ||e||^2 + counts/accum zeroing
__global__ void vq_conv(const float* __restrict__ emb, float* __restrict__ ws) {
  __shared__ short s_h[64][72], s_l[64][72];
  const int tid = threadIdx.x;
  const int mb = blockIdx.x * 64;  // 16 blocks x 64 codebook rows
  short* EH = (short*)(ws + WS_BF16_OFF);
  short* EL = EH + 65536;
  short* ETH = EL + 65536;
  short* ETL = ETH + 65536;
#pragma unroll
  for (int i = 0; i < 16; ++i) {
    int lin = tid + 256 * i;  // 0..4095 over (ml, d)
    int ml = lin >> 6, d = lin & 63;
    float v = emb[(size_t)(mb + ml) * 64 + d];
    short h = f2bfs(v);
    short l = f2bfs(v - bf2f(h));
    EH[(size_t)(mb + ml) * 64 + d] = h;
    EL[(size_t)(mb + ml) * 64 + d] = l;
    s_h[d][ml] = h;
    s_l[d][ml] = l;
  }
  if (tid < 64) {
    const float* e = emb + (size_t)(mb + tid) * 64;
    float s = 0.f;
#pragma unroll
    for (int d = 0; d < 64; d += 4) {
      float4 v = *(const float4*)(e + d);
      s += v.x * v.x + v.y * v.y + v.z * v.z + v.w * v.w;
    }
    ws[mb + tid] = s;
    ws[M_DIM + mb + tid] = 0.f;
  }
  if (blockIdx.x == 0 && tid == 0) ws[2 * M_DIM] = 0.f;
  __syncthreads();
#pragma unroll
  for (int i = 0; i < 16; ++i) {
    int lin = tid + 256 * i;  // now (d, ml)
    int d = lin >> 6, ml = lin & 63;
    ETH[(size_t)d * 1024 + mb + ml] = s_h[d][ml];
    ETL[(size_t)d * 1024 + mb + ml] = s_l[d][ml];
  }
}

__global__ __launch_bounds__(NT, 2) void vq_main(
    const float* __restrict__ x, const float* __restrict__ emb,
    const float* __restrict__ lvq, const float* __restrict__ gum,
    const float* __restrict__ temp, float* __restrict__ outq,
    float* __restrict__ ws) {
  __shared__ float s_sc[TR][SC_STRIDE];  // logits -> encodings -> q-partials
  __shared__ float s_x[TR][68];          // x tile (padded)
  __shared__ float s_xx[TR];
  __shared__ float s_red[8];

  const int tid = threadIdx.x;
  const int lane = tid & 63;
  const int wave = tid >> 6;   // 8 waves
  const int rg = wave >> 2;    // row-group 0/1 (16 tokens each)
  const int wl = wave & 3;     // m-range / K-range index
  const int mq = lane >> 4;    // quad 0..3
  const int mn = lane & 15;
  const int n0 = blockIdx.x * TR;
  const int b = n0 >> 12;
  const int t0 = n0 & (T_DIM - 1);
  const float precision = __expf(-lvq[0]);
  const float inv_temp = 1.0f / temp[0];
  const float* eew = ws;
  float* counts = ws + M_DIM;
  float* accum = ws + 2 * M_DIM;
  const short* EH = (const short*)(ws + WS_BF16_OFF);
  const short* EL = EH + 65536;
  const short* ETH = EL + 65536;
  const short* ETL = ETH + 65536;

  // ---- stage x tile: x[b][d][t0+tt] ----
  {
    int tt = tid & 31, d0 = tid >> 5;  // d0 in [0,16)
#pragma unroll
    for (int k = 0; k < 4; ++k) {
      int d = d0 + 16 * k;
      s_x[tt][d] = x[((size_t)b << 18) + ((size_t)d << 12) + (size_t)(t0 + tt)];
    }
  }
  __syncthreads();
  if (tid < TR) {
    float s = 0.f;
#pragma unroll
    for (int d = 0; d < D_DIM; ++d) { float v = s_x[tid][d]; s += v * v; }
    s_xx[tid] = s;
  }
  __syncthreads();

  // ---- GEMM1 (MFMA): logits[r][m] = precision*(x.e - 0.5||x||^2 - 0.5||e||^2)
  // wave (rg,wl): tokens 16rg..16rg+15, m in [256wl, 256wl+256) = 16 tiles; K=64
  // FULLY UNROLLED: acc[] must be compile-time indexed (partial unroll -> scratch!)
  {
    const int arow = rg * 16 + mn;
    bf16x8 ah0, al0, ah1, al1;
    cvt8(&s_x[arow][mq * 8], ah0, al0);        // k-step 0
    cvt8(&s_x[arow][32 + mq * 8], ah1, al1);   // k-step 1
    float xx4[4];
#pragma unroll
    for (int reg = 0; reg < 4; ++reg) xx4[reg] = s_xx[rg * 16 + mq * 4 + reg];
    f32x4 acc[16];
#pragma unroll
    for (int tt = 0; tt < 16; ++tt) acc[tt] = (f32x4){0.f, 0.f, 0.f, 0.f};
#pragma unroll
    for (int tt = 0; tt < 16; ++tt) {
      int m0 = wl * 256 + tt * 16;
      const short* bp = EH + (m0 + mn) * 64 + mq * 8;
      const short* lp = EL + (m0 + mn) * 64 + mq * 8;
      bf16x8 bh0 = *(const bf16x8*)bp;
      bf16x8 bh1 = *(const bf16x8*)(bp + 32);
      bf16x8 bl0 = *(const bf16x8*)lp;
      bf16x8 bl1 = *(const bf16x8*)(lp + 32);
      acc[tt] = __builtin_amdgcn_mfma_f32_16x16x32_bf16(ah0, bh0, acc[tt], 0, 0, 0);
      acc[tt] = __builtin_amdgcn_mfma_f32_16x16x32_bf16(ah1, bh1, acc[tt], 0, 0, 0);
      acc[tt] = __builtin_amdgcn_mfma_f32_16x16x32_bf16(al0, bh0, acc[tt], 0, 0, 0);
      acc[tt] = __builtin_amdgcn_mfma_f32_16x16x32_bf16(al1, bh1, acc[tt], 0, 0, 0);
      acc[tt] = __builtin_amdgcn_mfma_f32_16x16x32_bf16(ah0, bl0, acc[tt], 0, 0, 0);
      acc[tt] = __builtin_amdgcn_mfma_f32_16x16x32_bf16(ah1, bl1, acc[tt], 0, 0, 0);
    }
    // epilogue: C layout col=lane&15, row=(lane>>4)*4+reg (token = 16rg+row)
#pragma unroll
    for (int tt = 0; tt < 16; ++tt) {
      int m0 = wl * 256 + tt * 16;
      float eev = eew[m0 + mn];
#pragma unroll
      for (int reg = 0; reg < 4; ++reg) {
        int r = rg * 16 + mq * 4 + reg;
        s_sc[r][m0 + mn] = precision * (acc[tt][reg] - 0.5f * (xx4[reg] + eev));
      }
    }
  }
  __syncthreads();

  float partial = 0.f;

  // ---- phase 2: per-row softmaxes (wave w handles rows 4w..4w+3; 8x4=32) ----
  for (int rr = 0; rr < 4; ++rr) {
    int r = wave * 4 + rr;
    int n = n0 + r;
    float s[16], g[16];
#pragma unroll
    for (int k = 0; k < 4; ++k) {
      float4 v = *(const float4*)&s_sc[r][4 * lane + 256 * k];
      s[4 * k + 0] = v.x; s[4 * k + 1] = v.y; s[4 * k + 2] = v.z; s[4 * k + 3] = v.w;
    }
    float mx = -1e30f; int mi = 0;
#pragma unroll
    for (int i = 0; i < 16; ++i) {
      int m = 4 * lane + 256 * (i >> 2) + (i & 3);
      if (s[i] > mx) { mx = s[i]; mi = m; }
    }
#pragma unroll
    for (int off = 32; off; off >>= 1) {
      float omx = __shfl_xor(mx, off);
      int omi = __shfl_xor(mi, off);
      if (omx > mx || (omx == mx && omi < mi)) { mx = omx; mi = omi; }
    }
    const float* gn = gum + ((size_t)n << 10);
#pragma unroll
    for (int k = 0; k < 4; ++k) {
      float4 v = *(const float4*)(gn + 4 * lane + 256 * k);
      g[4 * k + 0] = v.x; g[4 * k + 1] = v.y; g[4 * k + 2] = v.z; g[4 * k + 3] = v.w;
    }
    float gmx = -1e30f;
#pragma unroll
    for (int i = 0; i < 16; ++i) {
      float gv = (s[i] + g[i]) * inv_temp;
      g[i] = gv;
      gmx = fmaxf(gmx, gv);
    }
#pragma unroll
    for (int off = 32; off; off >>= 1) gmx = fmaxf(gmx, __shfl_xor(gmx, off));
    float Zs = 0.f, As = 0.f, Zg = 0.f;
#pragma unroll
    for (int i = 0; i < 16; ++i) {
      float a = s[i] - mx;
      float e = __expf(a);
      Zs += e; As += a * e;
      float eg = __expf(g[i] - gmx);
      g[i] = eg;
      Zg += eg;
    }
#pragma unroll
    for (int off = 32; off; off >>= 1) {
      Zs += __shfl_xor(Zs, off);
      As += __shfl_xor(As, off);
      Zg += __shfl_xor(Zg, off);
    }
    float invZg = 1.0f / Zg;
#pragma unroll
    for (int k = 0; k < 4; ++k) {
      float4 w;
      w.x = g[4 * k + 0] * invZg; w.y = g[4 * k + 1] * invZg;
      w.z = g[4 * k + 2] * invZg; w.w = g[4 * k + 3] * invZg;
      *(float4*)&s_sc[r][4 * lane + 256 * k] = w;  // encodings overwrite logits
    }
    if (lane == 0) {
      partial += As / Zs - __logf(Zs);
      atomicAdd(counts + mi, 1.0f);
    }
  }
  __syncthreads();

  // ---- GEMM2 (MFMA): q[r][d] = sum_m P[r][m] * E[m][d]
  // wave (rg,wl): tokens 16rg..+15, K-range [256wl, 256wl+256) (8 k-steps)
  {
    f32x4 q[4];
#pragma unroll
    for (int nt = 0; nt < 4; ++nt) q[nt] = (f32x4){0.f, 0.f, 0.f, 0.f};
    const int arow = rg * 16 + mn;
    int k0w = wl * 256;
#pragma unroll 2
    for (int ks = 0; ks < 8; ++ks) {
      int k0 = k0w + ks * 32;
      bf16x8 ph, pl;
      cvt8(&s_sc[arow][k0 + mq * 8], ph, pl);  // A row = token, k-chunk
#pragma unroll
      for (int nt = 0; nt < 4; ++nt) {
        const short* bp = ETH + (nt * 16 + mn) * 1024 + k0 + mq * 8;
        const short* lp = ETL + (nt * 16 + mn) * 1024 + k0 + mq * 8;
        bf16x8 bh = *(const bf16x8*)bp;
        bf16x8 bl = *(const bf16x8*)lp;
        q[nt] = __builtin_amdgcn_mfma_f32_16x16x32_bf16(ph, bh, q[nt], 0, 0, 0);
        q[nt] = __builtin_amdgcn_mfma_f32_16x16x32_bf16(pl, bh, q[nt], 0, 0, 0);
        q[nt] = __builtin_amdgcn_mfma_f32_16x16x32_bf16(ph, bl, q[nt], 0, 0, 0);
      }
    }
    __syncthreads();  // all reads of s_sc (encodings) complete
    // partial q -> LDS overlay: qp[wl][token 0..31][68]
    float* qp = &s_sc[0][0];
#pragma unroll
    for (int nt = 0; nt < 4; ++nt)
#pragma unroll
      for (int reg = 0; reg < 4; ++reg)
        qp[(wl * 32 + rg * 16 + mq * 4 + reg) * 68 + nt * 16 + mn] = q[nt][reg];
  }
  __syncthreads();

  // ---- combine partials, write quantized (transposed), recon ----
  {
    int r = tid & 31, dq = tid >> 5;  // dq in [0,16): d = 4*dq
    const float* qp = &s_sc[0][0];
    float4 qs = {0.f, 0.f, 0.f, 0.f};
#pragma unroll
    for (int w = 0; w < 4; ++w) {
      float4 v = *(const float4*)&qp[(w * 32 + r) * 68 + 4 * dq];
      qs.x += v.x; qs.y += v.y; qs.z += v.z; qs.w += v.w;
    }
    int t = t0 + r;
    float* ob = outq + ((size_t)b << 18) + (size_t)t;
    int d = 4 * dq;
    ob[(size_t)(d + 0) << 12] = qs.x;
    ob[(size_t)(d + 1) << 12] = qs.y;
    ob[(size_t)(d + 2) << 12] = qs.z;
    ob[(size_t)(d + 3) << 12] = qs.w;
    float4 xv = *(const float4*)&s_x[r][d];
    float dx0 = xv.x - qs.x, dx1 = xv.y - qs.y, dx2 = xv.z - qs.z, dx3 = xv.w - qs.w;
    partial += 0.5f * precision * (dx0 * dx0 + dx1 * dx1 + dx2 * dx2 + dx3 * dx3);
  }
#pragma unroll
  for (int off = 32; off; off >>= 1) partial += __shfl_xor(partial, off);
  if (lane == 0) s_red[wave] = partial;
  __syncthreads();
  if (tid == 0) {
    float s = 0.f;
#pragma unroll
    for (int w = 0; w < 8; ++w) s += s_red[w];
    atomicAdd(accum, s);
  }
}

__global__ void vq_finalize(const float* __restrict__ ws, float* __restrict__ out) {
  __shared__ float red[4];
  int tid = threadIdx.x;
  float h = 0.f;
  for (int m = tid; m < M_DIM; m += 256) {
    float avg = ws[M_DIM + m] * (1.0f / 32768.0f);
    h += avg * __logf(avg + 1e-10f);
  }
#pragma unroll
  for (int off = 32; off; off >>= 1) h += __shfl_xor(h, off);
  int lane = tid & 63, wave = tid >> 6;
  if (lane == 0) red[wave] = h;
  __syncthreads();
  if (tid == 0) {
    out[0] = ws[2 * M_DIM] * 0.125f;                        // loss = total / B
    out[1] = __expf(-(red[0] + red[1] + red[2] + red[3]));  // perplexity
  }
}

extern "C" void kernel_launch(void* const* d_in, const int* in_sizes, int n_in,
                              void* d_out, int out_size, void* d_ws, size_t ws_size,
                              hipStream_t stream) {
  const float* x = (const float*)d_in[0];
  const float* emb = (const float*)d_in[1];
  const float* lvq = (const float*)d_in[2];
  const float* gum = (const float*)d_in[3];
  const float* temp = (const float*)d_in[4];
  float* out = (float*)d_out;
  float* ws = (float*)d_ws;

  hipLaunchKernelGGL(vq_conv, dim3(16), dim3(256), 0, stream, emb, ws);
  hipLaunchKernelGGL(vq_main, dim3(N_ROWS / TR), dim3(NT), 0, stream,
                     x, emb, lvq, gum, temp, out, ws);
  hipLaunchKernelGGL(vq_finalize, dim3(1), dim3(256), 0, stream, ws,
                     out + (size_t)2097152);
}

// Round 6
// 335.205 us; speedup vs baseline: 1.0067x; 1.0067x over previous
//
#include <hip/hip_runtime.h>

// Problem constants (B=8, T=4096, D=64, M=1024, N=32768)
#define T_DIM 4096
#define D_DIM 64
#define M_DIM 1024
#define N_ROWS 32768
#define TR 16   // rows (tokens) per workgroup
#define NT 256  // threads per block (4 waves)

typedef __attribute__((ext_vector_type(8))) short bf16x8;
typedef __attribute__((ext_vector_type(4))) float f32x4;

// ws layout: floats [0,1024)=||e||^2, [1024,2048)=counts, [2048]=loss accum.
// shorts from float index 4096: EH[65536], EL[65536], ETH[65536], ETL[65536]
#define WS_BF16_OFF 4096

__device__ __forceinline__ short f2bfs(float f) {
  union { float f; unsigned u; } v; v.f = f;
  unsigned r = v.u + 0x7fffu + ((v.u >> 16) & 1u);  // RNE
  return (short)(r >> 16);
}
__device__ __forceinline__ float bf2f(short h) {
  union { unsigned u; float f; } v; v.u = ((unsigned)(unsigned short)h) << 16;
  return v.f;
}
// 8 consecutive fp32 -> hi/lo bf16x8
__device__ __forceinline__ void cvt8(const float* p, bf16x8& h8, bf16x8& l8) {
  float4 a = *(const float4*)p, b = *(const float4*)(p + 4);
  float v[8] = {a.x, a.y, a.z, a.w, b.x, b.y, b.z, b.w};
#pragma unroll
  for (int i = 0; i < 8; ++i) {
    short h = f2bfs(v[i]);
    h8[i] = h;
    l8[i] = f2bfs(v[i] - bf2f(h));
  }
}

// split embedding into hi/lo bf16 (row-major + transposed), ||e||^2, zeroing
__global__ void vq_conv(const float* __restrict__ emb, float* __restrict__ ws) {
  __shared__ short s_h[64][72], s_l[64][72];
  const int tid = threadIdx.x;
  const int mb = blockIdx.x * 64;  // 16 blocks x 64 codebook rows
  short* EH = (short*)(ws + WS_BF16_OFF);
  short* EL = EH + 65536;
  short* ETH = EL + 65536;
  short* ETL = ETH + 65536;
#pragma unroll
  for (int i = 0; i < 16; ++i) {
    int lin = tid + 256 * i;  // 0..4095 over (ml, d)
    int ml = lin >> 6, d = lin & 63;
    float v = emb[(size_t)(mb + ml) * 64 + d];
    short h = f2bfs(v);
    short l = f2bfs(v - bf2f(h));
    EH[(size_t)(mb + ml) * 64 + d] = h;
    EL[(size_t)(mb + ml) * 64 + d] = l;
    s_h[d][ml] = h;
    s_l[d][ml] = l;
  }
  if (tid < 64) {
    const float* e = emb + (size_t)(mb + tid) * 64;
    float s = 0.f;
#pragma unroll
    for (int d = 0; d < 64; d += 4) {
      float4 v = *(const float4*)(e + d);
      s += v.x * v.x + v.y * v.y + v.z * v.z + v.w * v.w;
    }
    ws[mb + tid] = s;
    ws[M_DIM + mb + tid] = 0.f;
  }
  if (blockIdx.x == 0 && tid == 0) ws[2 * M_DIM] = 0.f;
  __syncthreads();
#pragma unroll
  for (int i = 0; i < 16; ++i) {
    int lin = tid + 256 * i;  // now (d, ml)
    int d = lin >> 6, ml = lin & 63;
    ETH[(size_t)d * 1024 + mb + ml] = s_h[d][ml];
    ETL[(size_t)d * 1024 + mb + ml] = s_l[d][ml];
  }
}

__global__ __launch_bounds__(NT, 4) void vq_main(
    const float* __restrict__ x, const float* __restrict__ emb,
    const float* __restrict__ lvq, const float* __restrict__ gum,
    const float* __restrict__ temp, float* __restrict__ outq,
    float* __restrict__ ws) {
  __shared__ float s_x[TR][68];         // x tile (padded)
  __shared__ float s_xx[TR];
  __shared__ float s_qp[4][TR][68];     // per-wave: P chunk transpose, then q partials
  __shared__ float s_stA_m[4][TR];      // per-wave per-token max
  __shared__ int   s_stA_i[4][TR];      // per-wave per-token argmax
  __shared__ float s_stB[4][TR][3];     // Zs, As, gmx
  __shared__ float s_stC[4][TR];        // Zg
  __shared__ float s_red[4];

  const int tid = threadIdx.x;
  const int lane = tid & 63;
  const int wl = tid >> 6;     // wave 0..3 : owns m/K range [256*wl, 256*wl+256)
  const int mq = lane >> 4;    // quad 0..3
  const int mn = lane & 15;
  const int n0 = blockIdx.x * TR;
  const int b = n0 >> 12;
  const int t0 = n0 & (T_DIM - 1);
  const float precision = __expf(-lvq[0]);
  const float inv_temp = 1.0f / temp[0];
  const float* eew = ws;
  float* counts = ws + M_DIM;
  float* accum = ws + 2 * M_DIM;
  const short* EH = (const short*)(ws + WS_BF16_OFF);
  const short* EL = EH + 65536;
  const short* ETH = EL + 65536;
  const short* ETL = ETH + 65536;

  // ---- stage x tile: x[b][d][t0+tt] ----
  {
    int tt = tid & 15, d0 = tid >> 4;
#pragma unroll
    for (int k = 0; k < 4; ++k) {
      int d = d0 + 16 * k;
      s_x[tt][d] = x[((size_t)b << 18) + ((size_t)d << 12) + (size_t)(t0 + tt)];
    }
  }
  __syncthreads();
  if (tid < TR) {
    float s = 0.f;
#pragma unroll
    for (int d = 0; d < D_DIM; ++d) { float v = s_x[tid][d]; s += v * v; }
    s_xx[tid] = s;
  }
  __syncthreads();

  // ---- GEMM1 (MFMA): logits stay in REGISTERS (C layout: col=mn->m, row=mq*4+reg->token)
  f32x4 acc[16];
  {
    bf16x8 ah0, al0, ah1, al1;
    cvt8(&s_x[mn][mq * 8], ah0, al0);        // k-step 0
    cvt8(&s_x[mn][32 + mq * 8], ah1, al1);   // k-step 1
#pragma unroll
    for (int tt = 0; tt < 16; ++tt) acc[tt] = (f32x4){0.f, 0.f, 0.f, 0.f};
#pragma unroll
    for (int tt = 0; tt < 16; ++tt) {
      int m0 = wl * 256 + tt * 16;
      const short* bp = EH + (m0 + mn) * 64 + mq * 8;
      const short* lp = EL + (m0 + mn) * 64 + mq * 8;
      bf16x8 bh0 = *(const bf16x8*)bp;
      bf16x8 bh1 = *(const bf16x8*)(bp + 32);
      bf16x8 bl0 = *(const bf16x8*)lp;
      bf16x8 bl1 = *(const bf16x8*)(lp + 32);
      acc[tt] = __builtin_amdgcn_mfma_f32_16x16x32_bf16(ah0, bh0, acc[tt], 0, 0, 0);
      acc[tt] = __builtin_amdgcn_mfma_f32_16x16x32_bf16(ah1, bh1, acc[tt], 0, 0, 0);
      acc[tt] = __builtin_amdgcn_mfma_f32_16x16x32_bf16(al0, bh0, acc[tt], 0, 0, 0);
      acc[tt] = __builtin_amdgcn_mfma_f32_16x16x32_bf16(al1, bh1, acc[tt], 0, 0, 0);
      acc[tt] = __builtin_amdgcn_mfma_f32_16x16x32_bf16(ah0, bl0, acc[tt], 0, 0, 0);
      acc[tt] = __builtin_amdgcn_mfma_f32_16x16x32_bf16(ah1, bl1, acc[tt], 0, 0, 0);
    }
    // epilogue in-register
    float xx4[4];
#pragma unroll
    for (int reg = 0; reg < 4; ++reg) xx4[reg] = s_xx[mq * 4 + reg];
#pragma unroll
    for (int tt = 0; tt < 16; ++tt) {
      float eev = eew[wl * 256 + tt * 16 + mn];
#pragma unroll
      for (int reg = 0; reg < 4; ++reg)
        acc[tt][reg] = precision * (acc[tt][reg] - 0.5f * (xx4[reg] + eev));
    }
  }

  // ---- R1: global max + argmax per token ----
  float Mx[4]; int Mi[4];
#pragma unroll
  for (int reg = 0; reg < 4; ++reg) {
    float mx = acc[0][reg]; int mi = wl * 256 + mn;
#pragma unroll
    for (int tt = 1; tt < 16; ++tt) {
      float v = acc[tt][reg];
      int m = wl * 256 + tt * 16 + mn;
      if (v > mx) { mx = v; mi = m; }
    }
#pragma unroll
    for (int off = 1; off <= 8; off <<= 1) {
      float omx = __shfl_xor(mx, off);
      int omi = __shfl_xor(mi, off);
      if (omx > mx || (omx == mx && omi < mi)) { mx = omx; mi = omi; }
    }
    if (mn == 0) { s_stA_m[wl][mq * 4 + reg] = mx; s_stA_i[wl][mq * 4 + reg] = mi; }
  }
  __syncthreads();
#pragma unroll
  for (int reg = 0; reg < 4; ++reg) {
    int token = mq * 4 + reg;
    Mx[reg] = s_stA_m[0][token]; Mi[reg] = s_stA_i[0][token];
#pragma unroll
    for (int w = 1; w < 4; ++w) {
      float m2 = s_stA_m[w][token]; int i2 = s_stA_i[w][token];
      if (m2 > Mx[reg] || (m2 == Mx[reg] && i2 < Mi[reg])) { Mx[reg] = m2; Mi[reg] = i2; }
    }
  }
  float partial = 0.f;
  if (wl == 0 && mn == 0) {
#pragma unroll
    for (int reg = 0; reg < 4; ++reg) atomicAdd(counts + Mi[reg], 1.0f);
  }

  // ---- transform: entropy accum + gumbelized logits (in-place) + local gumbel max ----
  float Zs[4] = {0.f, 0.f, 0.f, 0.f}, As[4] = {0.f, 0.f, 0.f, 0.f}, Gm[4];
#pragma unroll
  for (int reg = 0; reg < 4; ++reg) {
    const float* gp = gum + ((size_t)(n0 + mq * 4 + reg) << 10) + wl * 256 + mn;
    float gm = -1e30f;
#pragma unroll
    for (int tt = 0; tt < 16; ++tt) {
      float g = gp[tt * 16];
      float s = acc[tt][reg];
      float a = s - Mx[reg];
      float e = __expf(a);
      Zs[reg] += e; As[reg] += a * e;
      float gv = (s + g) * inv_temp;
      acc[tt][reg] = gv;
      gm = fmaxf(gm, gv);
    }
    Gm[reg] = gm;
  }
  // ---- R2: reduce (Zs, As, gmx) ----
#pragma unroll
  for (int reg = 0; reg < 4; ++reg) {
#pragma unroll
    for (int off = 1; off <= 8; off <<= 1) {
      Zs[reg] += __shfl_xor(Zs[reg], off);
      As[reg] += __shfl_xor(As[reg], off);
      Gm[reg] = fmaxf(Gm[reg], __shfl_xor(Gm[reg], off));
    }
    if (mn == 0) {
      s_stB[wl][mq * 4 + reg][0] = Zs[reg];
      s_stB[wl][mq * 4 + reg][1] = As[reg];
      s_stB[wl][mq * 4 + reg][2] = Gm[reg];
    }
  }
  __syncthreads();
  float GM[4];
#pragma unroll
  for (int reg = 0; reg < 4; ++reg) {
    int token = mq * 4 + reg;
    float zs = 0.f, as = 0.f, gmax = -1e30f;
#pragma unroll
    for (int w = 0; w < 4; ++w) {
      zs += s_stB[w][token][0];
      as += s_stB[w][token][1];
      gmax = fmaxf(gmax, s_stB[w][token][2]);
    }
    GM[reg] = gmax;
    if (wl == 0 && mn == 0) partial += as / zs - __logf(zs);
  }
  // ---- second exp pass: P (unnormalized) in-place; local Zg ----
  float Zg[4] = {0.f, 0.f, 0.f, 0.f};
#pragma unroll
  for (int tt = 0; tt < 16; ++tt) {
#pragma unroll
    for (int reg = 0; reg < 4; ++reg) {
      float p = __expf(acc[tt][reg] - GM[reg]);
      acc[tt][reg] = p;
      Zg[reg] += p;
    }
  }
  // ---- R3: reduce Zg ----
#pragma unroll
  for (int reg = 0; reg < 4; ++reg) {
#pragma unroll
    for (int off = 1; off <= 8; off <<= 1) Zg[reg] += __shfl_xor(Zg[reg], off);
    if (mn == 0) s_stC[wl][mq * 4 + reg] = Zg[reg];
  }
  __syncthreads();
  float invZg[4];
#pragma unroll
  for (int reg = 0; reg < 4; ++reg) {
    int token = mq * 4 + reg;
    float z = 0.f;
#pragma unroll
    for (int w = 0; w < 4; ++w) z += s_stC[w][token];
    invZg[reg] = 1.0f / z;
  }

  // ---- GEMM2 (MFMA): q[token][d] += P[token][m-chunk] * E[m-chunk][d]
  // per-wave K-split; P chunk-transposed C->A layout through own LDS buffer
  {
    f32x4 q[4];
#pragma unroll
    for (int nt = 0; nt < 4; ++nt) q[nt] = (f32x4){0.f, 0.f, 0.f, 0.f};
    float* sp = &s_qp[wl][0][0];  // used with stride 36 during transpose
#pragma unroll
    for (int ks = 0; ks < 8; ++ks) {
#pragma unroll
      for (int reg = 0; reg < 4; ++reg) {
        sp[(mq * 4 + reg) * 36 + mn]      = acc[2 * ks][reg] * invZg[reg];
        sp[(mq * 4 + reg) * 36 + 16 + mn] = acc[2 * ks + 1][reg] * invZg[reg];
      }
      bf16x8 ph, pl;
      cvt8(&sp[mn * 36 + mq * 8], ph, pl);  // A row = token mn, k = mq*8+j
      int k0 = wl * 256 + ks * 32;
#pragma unroll
      for (int nt = 0; nt < 4; ++nt) {
        const short* bp = ETH + (nt * 16 + mn) * 1024 + k0 + mq * 8;
        const short* lp = ETL + (nt * 16 + mn) * 1024 + k0 + mq * 8;
        bf16x8 bh = *(const bf16x8*)bp;
        bf16x8 bl = *(const bf16x8*)lp;
        q[nt] = __builtin_amdgcn_mfma_f32_16x16x32_bf16(ph, bh, q[nt], 0, 0, 0);
        q[nt] = __builtin_amdgcn_mfma_f32_16x16x32_bf16(pl, bh, q[nt], 0, 0, 0);
        q[nt] = __builtin_amdgcn_mfma_f32_16x16x32_bf16(ph, bl, q[nt], 0, 0, 0);
      }
    }
    // q partials -> own LDS region (C layout: token = mq*4+reg, d = nt*16+mn)
#pragma unroll
    for (int nt = 0; nt < 4; ++nt)
#pragma unroll
      for (int reg = 0; reg < 4; ++reg)
        s_qp[wl][mq * 4 + reg][nt * 16 + mn] = q[nt][reg];
  }
  __syncthreads();

  // ---- combine K-split partials, write quantized (transposed), recon ----
  {
    int r = tid & 15, dq = tid >> 4;  // consecutive lanes -> consecutive t
    float4 qs = {0.f, 0.f, 0.f, 0.f};
#pragma unroll
    for (int w = 0; w < 4; ++w) {
      float4 v = *(const float4*)&s_qp[w][r][4 * dq];
      qs.x += v.x; qs.y += v.y; qs.z += v.z; qs.w += v.w;
    }
    int t = t0 + r;
    float* ob = outq + ((size_t)b << 18) + (size_t)t;
    int d = 4 * dq;
    ob[(size_t)(d + 0) << 12] = qs.x;
    ob[(size_t)(d + 1) << 12] = qs.y;
    ob[(size_t)(d + 2) << 12] = qs.z;
    ob[(size_t)(d + 3) << 12] = qs.w;
    float4 xv = *(const float4*)&s_x[r][d];
    float dx0 = xv.x - qs.x, dx1 = xv.y - qs.y, dx2 = xv.z - qs.z, dx3 = xv.w - qs.w;
    partial += 0.5f * precision * (dx0 * dx0 + dx1 * dx1 + dx2 * dx2 + dx3 * dx3);
  }
#pragma unroll
  for (int off = 32; off; off >>= 1) partial += __shfl_xor(partial, off);
  if (lane == 0) s_red[wl] = partial;
  __syncthreads();
  if (tid == 0)
    atomicAdd(accum, s_red[0] + s_red[1] + s_red[2] + s_red[3]);
}

__global__ void vq_finalize(const float* __restrict__ ws, float* __restrict__ out) {
  __shared__ float red[4];
  int tid = threadIdx.x;
  float h = 0.f;
  for (int m = tid; m < M_DIM; m += 256) {
    float avg = ws[M_DIM + m] * (1.0f / 32768.0f);
    h += avg * __logf(avg + 1e-10f);
  }
#pragma unroll
  for (int off = 32; off; off >>= 1) h += __shfl_xor(h, off);
  int lane = tid & 63, wave = tid >> 6;
  if (lane == 0) red[wave] = h;
  __syncthreads();
  if (tid == 0) {
    out[0] = ws[2 * M_DIM] * 0.125f;                        // loss = total / B
    out[1] = __expf(-(red[0] + red[1] + red[2] + red[3]));  // perplexity
  }
}

extern "C" void kernel_launch(void* const* d_in, const int* in_sizes, int n_in,
                              void* d_out, int out_size, void* d_ws, size_t ws_size,
                              hipStream_t stream) {
  const float* x = (const float*)d_in[0];
  const float* emb = (const float*)d_in[1];
  const float* lvq = (const float*)d_in[2];
  const float* gum = (const float*)d_in[3];
  const float* temp = (const float*)d_in[4];
  float* out = (float*)d_out;
  float* ws = (float*)d_ws;

  hipLaunchKernelGGL(vq_conv, dim3(16), dim3(256), 0, stream, emb, ws);
  hipLaunchKernelGGL(vq_main, dim3(N_ROWS / TR), dim3(NT), 0, stream,
                     x, emb, lvq, gum, temp, out, ws);
  hipLaunchKernelGGL(vq_finalize, dim3(1), dim3(256), 0, stream, ws,
                     out + (size_t)2097152);
}

// Round 7
// 316.824 us; speedup vs baseline: 1.0651x; 1.0580x over previous
//
#include <hip/hip_runtime.h>

// Problem constants (B=8, T=4096, D=64, M=1024, N=32768)
#define T_DIM 4096
#define D_DIM 64
#define M_DIM 1024
#define N_ROWS 32768
#define TR 16   // rows (tokens) per workgroup
#define NT 512  // threads per block (8 waves)
#define NW 8    // waves

typedef __attribute__((ext_vector_type(8))) short bf16x8;
typedef __attribute__((ext_vector_type(4))) float f32x4;

// ws layout: floats [0,1024)=||e||^2, [1024,2048)=counts, [2048]=loss accum.
// shorts from float index 4096: EH[65536], EL[65536], ETH[65536], ETL[65536]
#define WS_BF16_OFF 4096

__device__ __forceinline__ short f2bfs(float f) {
  union { float f; unsigned u; } v; v.f = f;
  unsigned r = v.u + 0x7fffu + ((v.u >> 16) & 1u);  // RNE
  return (short)(r >> 16);
}
__device__ __forceinline__ float bf2f(short h) {
  union { unsigned u; float f; } v; v.u = ((unsigned)(unsigned short)h) << 16;
  return v.f;
}
// 8 consecutive fp32 -> hi/lo bf16x8
__device__ __forceinline__ void cvt8(const float* p, bf16x8& h8, bf16x8& l8) {
  float4 a = *(const float4*)p, b = *(const float4*)(p + 4);
  float v[8] = {a.x, a.y, a.z, a.w, b.x, b.y, b.z, b.w};
#pragma unroll
  for (int i = 0; i < 8; ++i) {
    short h = f2bfs(v[i]);
    h8[i] = h;
    l8[i] = f2bfs(v[i] - bf2f(h));
  }
}

// split embedding into hi/lo bf16 (row-major + transposed), ||e||^2, zeroing
__global__ void vq_conv(const float* __restrict__ emb, float* __restrict__ ws) {
  __shared__ short s_h[64][72], s_l[64][72];
  const int tid = threadIdx.x;
  const int mb = blockIdx.x * 64;  // 16 blocks x 64 codebook rows
  short* EH = (short*)(ws + WS_BF16_OFF);
  short* EL = EH + 65536;
  short* ETH = EL + 65536;
  short* ETL = ETH + 65536;
#pragma unroll
  for (int i = 0; i < 16; ++i) {
    int lin = tid + 256 * i;  // 0..4095 over (ml, d)
    int ml = lin >> 6, d = lin & 63;
    float v = emb[(size_t)(mb + ml) * 64 + d];
    short h = f2bfs(v);
    short l = f2bfs(v - bf2f(h));
    EH[(size_t)(mb + ml) * 64 + d] = h;
    EL[(size_t)(mb + ml) * 64 + d] = l;
    s_h[d][ml] = h;
    s_l[d][ml] = l;
  }
  if (tid < 64) {
    const float* e = emb + (size_t)(mb + tid) * 64;
    float s = 0.f;
#pragma unroll
    for (int d = 0; d < 64; d += 4) {
      float4 v = *(const float4*)(e + d);
      s += v.x * v.x + v.y * v.y + v.z * v.z + v.w * v.w;
    }
    ws[mb + tid] = s;
    ws[M_DIM + mb + tid] = 0.f;
  }
  if (blockIdx.x == 0 && tid == 0) ws[2 * M_DIM] = 0.f;
  __syncthreads();
#pragma unroll
  for (int i = 0; i < 16; ++i) {
    int lin = tid + 256 * i;  // now (d, ml)
    int d = lin >> 6, ml = lin & 63;
    ETH[(size_t)d * 1024 + mb + ml] = s_h[d][ml];
    ETL[(size_t)d * 1024 + mb + ml] = s_l[d][ml];
  }
}

__global__ __launch_bounds__(NT, 4) void vq_main(
    const float* __restrict__ x, const float* __restrict__ emb,
    const float* __restrict__ lvq, const float* __restrict__ gum,
    const float* __restrict__ temp, float* __restrict__ outq,
    float* __restrict__ ws) {
  __shared__ float s_x[TR][68];          // x tile (padded)
  __shared__ float s_xx[TR];
  __shared__ float s_qp[NW][TR][68];     // per-wave: P chunk transpose, then q partials
  __shared__ float s_stA_m[NW][TR];      // per-wave per-token max
  __shared__ int   s_stA_i[NW][TR];      // per-wave per-token argmax
  __shared__ float s_stB[NW][TR][3];     // Zs, As, gmx
  __shared__ float s_stC[NW][TR];        // Zg
  __shared__ float s_red[NW];

  const int tid = threadIdx.x;
  const int lane = tid & 63;
  const int wl = tid >> 6;     // wave 0..7 : owns m/K range [128*wl, 128*wl+128)
  const int mq = lane >> 4;    // quad 0..3
  const int mn = lane & 15;
  const int n0 = blockIdx.x * TR;
  const int b = n0 >> 12;
  const int t0 = n0 & (T_DIM - 1);
  const float precision = __expf(-lvq[0]);
  const float inv_temp = 1.0f / temp[0];
  const float* eew = ws;
  float* counts = ws + M_DIM;
  float* accum = ws + 2 * M_DIM;
  const short* EH = (const short*)(ws + WS_BF16_OFF);
  const short* EL = EH + 65536;
  const short* ETH = EL + 65536;
  const short* ETL = ETH + 65536;

  // ---- stage x tile: x[b][d][t0+tt] ----
  {
    int tt = tid & 15, d0 = tid >> 4;  // d0 in [0,32)
    s_x[tt][d0] = x[((size_t)b << 18) + ((size_t)d0 << 12) + (size_t)(t0 + tt)];
    s_x[tt][d0 + 32] =
        x[((size_t)b << 18) + ((size_t)(d0 + 32) << 12) + (size_t)(t0 + tt)];
  }
  __syncthreads();
  if (tid < TR) {
    float s = 0.f;
#pragma unroll
    for (int d = 0; d < D_DIM; ++d) { float v = s_x[tid][d]; s += v * v; }
    s_xx[tid] = s;
  }
  __syncthreads();

  // ---- GEMM1 (MFMA): logits in REGISTERS (C layout: col=mn->m, row=mq*4+reg->token)
  // wave wl: 8 m-tiles of 16; K=64 = 2 k-steps; 32 score VGPRs/thread
  f32x4 acc[8];
  {
    bf16x8 ah0, al0, ah1, al1;
    cvt8(&s_x[mn][mq * 8], ah0, al0);        // k-step 0
    cvt8(&s_x[mn][32 + mq * 8], ah1, al1);   // k-step 1
#pragma unroll
    for (int tt = 0; tt < 8; ++tt) acc[tt] = (f32x4){0.f, 0.f, 0.f, 0.f};
#pragma unroll
    for (int tt = 0; tt < 8; ++tt) {
      int m0 = wl * 128 + tt * 16;
      const short* bp = EH + (m0 + mn) * 64 + mq * 8;
      const short* lp = EL + (m0 + mn) * 64 + mq * 8;
      bf16x8 bh0 = *(const bf16x8*)bp;
      bf16x8 bh1 = *(const bf16x8*)(bp + 32);
      bf16x8 bl0 = *(const bf16x8*)lp;
      bf16x8 bl1 = *(const bf16x8*)(lp + 32);
      acc[tt] = __builtin_amdgcn_mfma_f32_16x16x32_bf16(ah0, bh0, acc[tt], 0, 0, 0);
      acc[tt] = __builtin_amdgcn_mfma_f32_16x16x32_bf16(ah1, bh1, acc[tt], 0, 0, 0);
      acc[tt] = __builtin_amdgcn_mfma_f32_16x16x32_bf16(al0, bh0, acc[tt], 0, 0, 0);
      acc[tt] = __builtin_amdgcn_mfma_f32_16x16x32_bf16(al1, bh1, acc[tt], 0, 0, 0);
      acc[tt] = __builtin_amdgcn_mfma_f32_16x16x32_bf16(ah0, bl0, acc[tt], 0, 0, 0);
      acc[tt] = __builtin_amdgcn_mfma_f32_16x16x32_bf16(ah1, bl1, acc[tt], 0, 0, 0);
    }
    // epilogue in-register
    float xx4[4];
#pragma unroll
    for (int reg = 0; reg < 4; ++reg) xx4[reg] = s_xx[mq * 4 + reg];
#pragma unroll
    for (int tt = 0; tt < 8; ++tt) {
      float eev = eew[wl * 128 + tt * 16 + mn];
#pragma unroll
      for (int reg = 0; reg < 4; ++reg)
        acc[tt][reg] = precision * (acc[tt][reg] - 0.5f * (xx4[reg] + eev));
    }
  }

  // ---- R1: global max + argmax per token ----
  float Mx[4]; int Mi[4];
#pragma unroll
  for (int reg = 0; reg < 4; ++reg) {
    float mx = acc[0][reg]; int mi = wl * 128 + mn;
#pragma unroll
    for (int tt = 1; tt < 8; ++tt) {
      float v = acc[tt][reg];
      int m = wl * 128 + tt * 16 + mn;
      if (v > mx) { mx = v; mi = m; }
    }
#pragma unroll
    for (int off = 1; off <= 8; off <<= 1) {
      float omx = __shfl_xor(mx, off);
      int omi = __shfl_xor(mi, off);
      if (omx > mx || (omx == mx && omi < mi)) { mx = omx; mi = omi; }
    }
    if (mn == 0) { s_stA_m[wl][mq * 4 + reg] = mx; s_stA_i[wl][mq * 4 + reg] = mi; }
  }
  __syncthreads();
#pragma unroll
  for (int reg = 0; reg < 4; ++reg) {
    int token = mq * 4 + reg;
    Mx[reg] = s_stA_m[0][token]; Mi[reg] = s_stA_i[0][token];
#pragma unroll
    for (int w = 1; w < NW; ++w) {
      float m2 = s_stA_m[w][token]; int i2 = s_stA_i[w][token];
      if (m2 > Mx[reg] || (m2 == Mx[reg] && i2 < Mi[reg])) { Mx[reg] = m2; Mi[reg] = i2; }
    }
  }
  float partial = 0.f;
  if (wl == 0 && mn == 0) {
#pragma unroll
    for (int reg = 0; reg < 4; ++reg) atomicAdd(counts + Mi[reg], 1.0f);
  }

  // ---- transform: entropy accum + gumbelized logits (in-place) + local gumbel max ----
  float Zs[4] = {0.f, 0.f, 0.f, 0.f}, As[4] = {0.f, 0.f, 0.f, 0.f}, Gm[4];
#pragma unroll
  for (int reg = 0; reg < 4; ++reg) {
    const float* gp = gum + ((size_t)(n0 + mq * 4 + reg) << 10) + wl * 128 + mn;
    float gm = -1e30f;
#pragma unroll
    for (int tt = 0; tt < 8; ++tt) {
      float g = gp[tt * 16];
      float s = acc[tt][reg];
      float a = s - Mx[reg];
      float e = __expf(a);
      Zs[reg] += e; As[reg] += a * e;
      float gv = (s + g) * inv_temp;
      acc[tt][reg] = gv;
      gm = fmaxf(gm, gv);
    }
    Gm[reg] = gm;
  }
  // ---- R2: reduce (Zs, As, gmx) ----
#pragma unroll
  for (int reg = 0; reg < 4; ++reg) {
#pragma unroll
    for (int off = 1; off <= 8; off <<= 1) {
      Zs[reg] += __shfl_xor(Zs[reg], off);
      As[reg] += __shfl_xor(As[reg], off);
      Gm[reg] = fmaxf(Gm[reg], __shfl_xor(Gm[reg], off));
    }
    if (mn == 0) {
      s_stB[wl][mq * 4 + reg][0] = Zs[reg];
      s_stB[wl][mq * 4 + reg][1] = As[reg];
      s_stB[wl][mq * 4 + reg][2] = Gm[reg];
    }
  }
  __syncthreads();
  float GM[4];
#pragma unroll
  for (int reg = 0; reg < 4; ++reg) {
    int token = mq * 4 + reg;
    float zs = 0.f, as = 0.f, gmax = -1e30f;
#pragma unroll
    for (int w = 0; w < NW; ++w) {
      zs += s_stB[w][token][0];
      as += s_stB[w][token][1];
      gmax = fmaxf(gmax, s_stB[w][token][2]);
    }
    GM[reg] = gmax;
    if (wl == 0 && mn == 0) partial += as / zs - __logf(zs);
  }
  // ---- second exp pass: P (unnormalized) in-place; local Zg ----
  float Zg[4] = {0.f, 0.f, 0.f, 0.f};
#pragma unroll
  for (int tt = 0; tt < 8; ++tt) {
#pragma unroll
    for (int reg = 0; reg < 4; ++reg) {
      float p = __expf(acc[tt][reg] - GM[reg]);
      acc[tt][reg] = p;
      Zg[reg] += p;
    }
  }
  // ---- R3: reduce Zg ----
#pragma unroll
  for (int reg = 0; reg < 4; ++reg) {
#pragma unroll
    for (int off = 1; off <= 8; off <<= 1) Zg[reg] += __shfl_xor(Zg[reg], off);
    if (mn == 0) s_stC[wl][mq * 4 + reg] = Zg[reg];
  }
  __syncthreads();
  float invZg[4];
#pragma unroll
  for (int reg = 0; reg < 4; ++reg) {
    int token = mq * 4 + reg;
    float z = 0.f;
#pragma unroll
    for (int w = 0; w < NW; ++w) z += s_stC[w][token];
    invZg[reg] = 1.0f / z;
  }

  // ---- GEMM2 (MFMA): q[token][d] += P[token][k-chunk] * E[k-chunk][d]
  // wave wl owns K-range [128wl, 128wl+128) = 4 k-steps of 32
  {
    f32x4 q[4];
#pragma unroll
    for (int nt = 0; nt < 4; ++nt) q[nt] = (f32x4){0.f, 0.f, 0.f, 0.f};
    float* sp = &s_qp[wl][0][0];  // stride-36 scratch during transpose
#pragma unroll
    for (int ks = 0; ks < 4; ++ks) {
#pragma unroll
      for (int reg = 0; reg < 4; ++reg) {
        sp[(mq * 4 + reg) * 36 + mn]      = acc[2 * ks][reg] * invZg[reg];
        sp[(mq * 4 + reg) * 36 + 16 + mn] = acc[2 * ks + 1][reg] * invZg[reg];
      }
      bf16x8 ph, pl;
      cvt8(&sp[mn * 36 + mq * 8], ph, pl);  // A row = token mn, k = mq*8+j
      int k0 = wl * 128 + ks * 32;
#pragma unroll
      for (int nt = 0; nt < 4; ++nt) {
        const short* bp = ETH + (nt * 16 + mn) * 1024 + k0 + mq * 8;
        const short* lp = ETL + (nt * 16 + mn) * 1024 + k0 + mq * 8;
        bf16x8 bh = *(const bf16x8*)bp;
        bf16x8 bl = *(const bf16x8*)lp;
        q[nt] = __builtin_amdgcn_mfma_f32_16x16x32_bf16(ph, bh, q[nt], 0, 0, 0);
        q[nt] = __builtin_amdgcn_mfma_f32_16x16x32_bf16(pl, bh, q[nt], 0, 0, 0);
        q[nt] = __builtin_amdgcn_mfma_f32_16x16x32_bf16(ph, bl, q[nt], 0, 0, 0);
      }
    }
    // q partials -> own LDS region (C layout: token = mq*4+reg, d = nt*16+mn)
#pragma unroll
    for (int nt = 0; nt < 4; ++nt)
#pragma unroll
      for (int reg = 0; reg < 4; ++reg)
        s_qp[wl][mq * 4 + reg][nt * 16 + mn] = q[nt][reg];
  }
  __syncthreads();

  // ---- combine K-split partials, write quantized (transposed), recon ----
  if (tid < 256) {
    int r = tid & 15, dq = tid >> 4;  // consecutive lanes -> consecutive t
    float4 qs = {0.f, 0.f, 0.f, 0.f};
#pragma unroll
    for (int w = 0; w < NW; ++w) {
      float4 v = *(const float4*)&s_qp[w][r][4 * dq];
      qs.x += v.x; qs.y += v.y; qs.z += v.z; qs.w += v.w;
    }
    int t = t0 + r;
    float* ob = outq + ((size_t)b << 18) + (size_t)t;
    int d = 4 * dq;
    ob[(size_t)(d + 0) << 12] = qs.x;
    ob[(size_t)(d + 1) << 12] = qs.y;
    ob[(size_t)(d + 2) << 12] = qs.z;
    ob[(size_t)(d + 3) << 12] = qs.w;
    float4 xv = *(const float4*)&s_x[r][d];
    float dx0 = xv.x - qs.x, dx1 = xv.y - qs.y, dx2 = xv.z - qs.z, dx3 = xv.w - qs.w;
    partial += 0.5f * precision * (dx0 * dx0 + dx1 * dx1 + dx2 * dx2 + dx3 * dx3);
  }
#pragma unroll
  for (int off = 32; off; off >>= 1) partial += __shfl_xor(partial, off);
  if (lane == 0) s_red[wl] = partial;
  __syncthreads();
  if (tid == 0) {
    float s = 0.f;
#pragma unroll
    for (int w = 0; w < NW; ++w) s += s_red[w];
    atomicAdd(accum, s);
  }
}

__global__ void vq_finalize(const float* __restrict__ ws, float* __restrict__ out) {
  __shared__ float red[4];
  int tid = threadIdx.x;
  float h = 0.f;
  for (int m = tid; m < M_DIM; m += 256) {
    float avg = ws[M_DIM + m] * (1.0f / 32768.0f);
    h += avg * __logf(avg + 1e-10f);
  }
#pragma unroll
  for (int off = 32; off; off >>= 1) h += __shfl_xor(h, off);
  int lane = tid & 63, wave = tid >> 6;
  if (lane == 0) red[wave] = h;
  __syncthreads();
  if (tid == 0) {
    out[0] = ws[2 * M_DIM] * 0.125f;                        // loss = total / B
    out[1] = __expf(-(red[0] + red[1] + red[2] + red[3]));  // perplexity
  }
}

extern "C" void kernel_launch(void* const* d_in, const int* in_sizes, int n_in,
                              void* d_out, int out_size, void* d_ws, size_t ws_size,
                              hipStream_t stream) {
  const float* x = (const float*)d_in[0];
  const float* emb = (const float*)d_in[1];
  const float* lvq = (const float*)d_in[2];
  const float* gum = (const float*)d_in[3];
  const float* temp = (const float*)d_in[4];
  float* out = (float*)d_out;
  float* ws = (float*)d_ws;

  hipLaunchKernelGGL(vq_conv, dim3(16), dim3(256), 0, stream, emb, ws);
  hipLaunchKernelGGL(vq_main, dim3(N_ROWS / TR), dim3(NT), 0, stream,
                     x, emb, lvq, gum, temp, out, ws);
  hipLaunchKernelGGL(vq_finalize, dim3(1), dim3(256), 0, stream, ws,
                     out + (size_t)2097152);
}